// Round 7
// baseline (4915.602 us; speedup 1.0000x reference)
//
#include <hip/hip_runtime.h>
#include <math.h>

using bf16x8 = __attribute__((ext_vector_type(8))) short;
using short16 = __attribute__((ext_vector_type(16))) short;
using f32x4  = __attribute__((ext_vector_type(4))) float;
typedef unsigned short us;
typedef unsigned long long u64;

__device__ __forceinline__ float sigf(float x){ return 1.f/(1.f+expf(-x)); }

__device__ __forceinline__ us f2bf(float x){
  union { float f; unsigned u; } v; v.f = x;
  unsigned r = v.u + 0x7FFF + ((v.u>>16)&1);
  return (us)(r>>16);
}
__device__ __forceinline__ float bf2f(us h){
  union { unsigned u; float f; } v; v.u = ((unsigned)h)<<16; return v.f;
}

__device__ __forceinline__ void mfma3(f32x4& acc, bf16x8 ah, bf16x8 al, bf16x8 bh, bf16x8 bl){
  acc = __builtin_amdgcn_mfma_f32_16x16x32_bf16(ah, bh, acc, 0,0,0);
  acc = __builtin_amdgcn_mfma_f32_16x16x32_bf16(ah, bl, acc, 0,0,0);
  acc = __builtin_amdgcn_mfma_f32_16x16x32_bf16(al, bh, acc, 0,0,0);
}

// fence-free grid barrier: h is exchanged via sc1 (MALL-coherent) atomics, so no
// L2 writeback/invalidate is needed — W/X stay L2-resident across steps.
// __syncthreads() provides the vmcnt(0) drain of the sc1 h-stores before the add.
__device__ __forceinline__ void grid_sync(unsigned* c, unsigned target){
  __syncthreads();
  if (threadIdx.x == 0){
    __hip_atomic_fetch_add(c, 1u, __ATOMIC_RELAXED, __HIP_MEMORY_SCOPE_AGENT);
    while (__hip_atomic_load(c, __ATOMIC_RELAXED, __HIP_MEMORY_SCOPE_AGENT) < target)
      __builtin_amdgcn_s_sleep(2);
  }
  __syncthreads();
}

// ---------------- zero fill ----------------
__global__ void zero_k(float* __restrict__ p, long n){
  long i = (long)blockIdx.x*blockDim.x + threadIdx.x;
  long stride = (long)gridDim.x*blockDim.x;
  for (; i<n; i+=stride) p[i] = 0.f;
}

// ---------------- fp32 -> bf16 hi + lo ----------------
__global__ void split_k(const float* __restrict__ in, us* __restrict__ hi,
                        us* __restrict__ lo, long n){
  long i = (long)blockIdx.x*blockDim.x + threadIdx.x;
  long stride = (long)gridDim.x*blockDim.x;
  for (; i<n; i+=stride){
    float x = in[i];
    us h = f2bf(x);
    hi[i] = h;
    lo[i] = f2bf(x - bf2f(h));
  }
}

// ---- permute+split scan weights: out[nb*64 + g*16 + jl][c] = (c<KH ? Whh : Wih)[g*H + nb*16 + jl][...]
__global__ void permsplit_k(const float* __restrict__ Whh, const float* __restrict__ Wih,
                            us* __restrict__ hi, us* __restrict__ lo, int H, int KH, int KX){
  int KHX = KH + KX;
  long total = (long)4*H*KHX;
  long i = (long)blockIdx.x*blockDim.x + threadIdx.x;
  long stride = (long)gridDim.x*blockDim.x;
  for (; i<total; i+=stride){
    int c = (int)(i % KHX);
    int r = (int)(i / KHX);
    int nb = r >> 6, rem = r & 63, g = rem >> 4, jl = rem & 15;
    int in_row = g*H + nb*16 + jl;
    float v = (c < KH) ? Whh[(long)in_row*KH + c] : Wih[(long)in_row*KX + (c-KH)];
    us h = f2bf(v);
    hi[i] = h;
    lo[i] = f2bf(v - bf2f(h));
  }
}

// ---------------- emb[b][d] = lang_embeds[ li[li[b]] ][d] ----------------
__global__ void emb_k(const int* __restrict__ li, const float* __restrict__ le, float* __restrict__ emb){
  int b = blockIdx.x, d = threadIdx.x;
  int idx = li[li[b]];
  emb[b*64+d] = le[idx*64+d];
}

// ---------------- out[b][s][0:D1]=seq, [D1:D1+D2]=emb[b]  (bf16 hi/lo out) ----------------
__global__ void build_concat_k(const float* __restrict__ seq, const float* __restrict__ emb,
                               us* __restrict__ hi, us* __restrict__ lo,
                               int S, int D1, int D2, long total){
  long i = (long)blockIdx.x*blockDim.x + threadIdx.x;
  if (i>=total) return;
  int D = D1+D2;
  int d = (int)(i % D);
  long bs = i / D;
  int s = (int)(bs % S);
  int b = (int)(bs / S);
  float v = (d<D1) ? seq[((long)b*S+s)*D1 + d] : emb[b*64 + (d-D1)];
  us h = f2bf(v);
  hi[i] = h;
  lo[i] = f2bf(v - bf2f(h));
}

// ======================= persistent LSTM scan =======================
// h state: packed u32 per element = hi | (lo<<16), exchanged via agent-scope (sc1/MALL)
// atomics so no device fence (no L2 invalidation) is needed at the per-step barrier.
struct ScanDir {
  const us* Whi; const us* Wlo;   // [4H][KH+KX], gate-interleaved permuted rows
  const float* bias;              // [4H] original layout
  const us* Xh; const us* Xl; long ldx; int xrev; int skip_x_t0;
  unsigned* hpkA; unsigned* hpkB; int ldw;   // packed h double buffer (pre-offset by col)
  const float* c0; float* cfin;   // c init/final (ld 512, pre-offset)
  us* out; int ldo; long otstride;
  int H; int nWG;
};

template<int KH, int KX>
__global__ __launch_bounds__(256) void scan_k(ScanDir d0, ScanDir d1, int ndir,
                                              int nsteps, int nwg_total, unsigned* counter)
{
  constexpr int KHX = KH + KX;
  constexpr bool XL = (KHX <= 512);       // whole W-hi slice fits 64KB LDS?
  constexpr int LDSC = XL ? KHX : KH;
  __shared__ us Wsh[64*LDSC];
  ScanDir d = d0;
  int lwg = blockIdx.x;
  if (ndir == 2 && lwg >= d0.nWG){ d = d1; lwg -= d0.nWG; }
  const int H = d.H;
  int nnb = H >> 4;
  int nb = lwg % nnb, mb = lwg / nnb;
  int lane = threadIdx.x & 63, w = threadIdx.x >> 6;
  int lrow = lane & 15, klane = (lane >> 4) * 8;
  int rowbase = mb*128 + w*32;
  int jj = nb*16 + lrow;

  // stage hi-limb W slice into LDS, XOR-swizzled
  const us* wsrc = d.Whi + (long)(nb*64)*KHX;
  for (int ci = threadIdx.x; ci < 64*(LDSC/8); ci += 256){
    int r = ci / (LDSC/8), cb = ci % (LDSC/8);
    bf16x8 v = *(const bf16x8*)(wsrc + (long)r*KHX + cb*8);
    int byte = r*(LDSC*2) + cb*16;
    byte ^= (r & 7) << 4;
    *(bf16x8*)((char*)Wsh + byte) = v;
  }
  float bg[4];
  #pragma unroll
  for (int g=0; g<4; ++g) bg[g] = d.bias[g*H + jj];
  float creg[2][4];
  #pragma unroll
  for (int m=0;m<2;m++)
    #pragma unroll
    for (int r=0;r<4;r++){
      int row = rowbase + m*16 + (lane>>4)*4 + r;
      creg[m][r] = d.c0 ? d.c0[(long)row*512 + jj] : 0.f;
    }
  __syncthreads();

  const us* Wlo_base = d.Wlo + (long)(nb*64)*KHX;

  for (int t=0; t<nsteps; ++t){
    const unsigned* Rpk = (t&1) ? d.hpkB : d.hpkA;
    unsigned*       Wpk = (t&1) ? d.hpkA : d.hpkB;
    int teff = d.xrev ? (nsteps-1-t) : t;
    f32x4 acc[2][4] = {};
    // recurrent part: gates += h @ W_hh'   (h via sc1/MALL atomic loads)
    for (int k0=0; k0<KH; k0+=32){
      bf16x8 ah[2], al[2];
      #pragma unroll
      for (int m=0;m<2;m++){
        const unsigned* hp = Rpk + (long)(rowbase + m*16 + lrow)*d.ldw + k0 + klane;
        union { u64 q[4]; short16 s; } uu;
        uu.q[0] = __hip_atomic_load((const u64*)(hp+0), __ATOMIC_RELAXED, __HIP_MEMORY_SCOPE_AGENT);
        uu.q[1] = __hip_atomic_load((const u64*)(hp+2), __ATOMIC_RELAXED, __HIP_MEMORY_SCOPE_AGENT);
        uu.q[2] = __hip_atomic_load((const u64*)(hp+4), __ATOMIC_RELAXED, __HIP_MEMORY_SCOPE_AGENT);
        uu.q[3] = __hip_atomic_load((const u64*)(hp+6), __ATOMIC_RELAXED, __HIP_MEMORY_SCOPE_AGENT);
        ah[m] = __builtin_shufflevector(uu.s, uu.s, 0,2,4,6,8,10,12,14);
        al[m] = __builtin_shufflevector(uu.s, uu.s, 1,3,5,7,9,11,13,15);
      }
      #pragma unroll
      for (int nf=0; nf<4; nf++){
        int rB = nf*16 + lrow;
        int byte = rB*(LDSC*2) + (k0 + klane)*2;
        byte ^= (rB & 7) << 4;
        bf16x8 bh = *(const bf16x8*)((const char*)Wsh + byte);
        bf16x8 bl = *(const bf16x8*)(Wlo_base + (long)rB*KHX + k0 + klane);
        #pragma unroll
        for (int m=0;m<2;m++) mfma3(acc[m][nf], ah[m], al[m], bh, bl);
      }
    }
    // input part: gates += x_t @ W_ih'  (normal cached loads; L2-resident now)
    if (!(d.skip_x_t0 && t==0)){
      long xoff = (long)teff*KX;
      for (int k0=0; k0<KX; k0+=32){
        bf16x8 ah[2], al[2];
        #pragma unroll
        for (int m=0;m<2;m++){
          long ao = (long)(rowbase + m*16 + lrow)*d.ldx + xoff + k0 + klane;
          ah[m] = *(const bf16x8*)(d.Xh + ao);
          al[m] = *(const bf16x8*)(d.Xl + ao);
        }
        #pragma unroll
        for (int nf=0; nf<4; nf++){
          int rB = nf*16 + lrow;
          bf16x8 bh;
          if (XL){
            int byte = rB*(LDSC*2) + (KH + k0 + klane)*2;
            byte ^= (rB & 7) << 4;
            bh = *(const bf16x8*)((const char*)Wsh + byte);
          } else {
            bh = *(const bf16x8*)(d.Whi + (long)(nb*64 + rB)*KHX + KH + k0 + klane);
          }
          bf16x8 bl = *(const bf16x8*)(Wlo_base + (long)rB*KHX + KH + k0 + klane);
          #pragma unroll
          for (int m=0;m<2;m++) mfma3(acc[m][nf], ah[m], al[m], bh, bl);
        }
      }
    }
    // activation (gate g == n-fragment nf thanks to permuted W rows)
    int last = (t == nsteps-1);
    #pragma unroll
    for (int m=0;m<2;m++){
      #pragma unroll
      for (int r=0;r<4;r++){
        int row = rowbase + m*16 + (lane>>4)*4 + r;
        float gi = acc[m][0][r] + bg[0];
        float gf = acc[m][1][r] + bg[1];
        float gg = acc[m][2][r] + bg[2];
        float go = acc[m][3][r] + bg[3];
        float cn = sigf(gf)*creg[m][r] + sigf(gi)*tanhf(gg);
        float hn = sigf(go)*tanhf(cn);
        creg[m][r] = cn;
        us hh = f2bf(hn);
        unsigned pk = (unsigned)hh | ((unsigned)f2bf(hn - bf2f(hh)) << 16);
        __hip_atomic_store(Wpk + (long)row*d.ldw + jj, pk, __ATOMIC_RELAXED, __HIP_MEMORY_SCOPE_AGENT);
        d.out[(long)teff*d.otstride + (long)row*d.ldo + jj] = hh;
        if (last && d.cfin) d.cfin[(long)row*512 + jj] = cn;
      }
    }
    if (t+1 < nsteps) grid_sync(counter, (unsigned)((t+1)*nwg_total));
  }
}

// ------- split-bf16 MFMA GEMM (128x128 tile): C[M,N] = (Ah+Al) @ (Wh+Wl)^T (+bias) -------
template<int AS>
__global__ __launch_bounds__(256) void gemm_ms_k(
    const us* __restrict__ Ah, const us* __restrict__ Al,
    const us* __restrict__ Wh, const us* __restrict__ Wl,
    float* __restrict__ Cf, us* __restrict__ Chi, us* __restrict__ Clo,
    const float* __restrict__ bias,
    int M, int N, int K, int lda, int ldb, int ldc, int accf)
{
  int bm = blockIdx.y*128, bn = blockIdx.x*128;
  int wid = threadIdx.x >> 6, lane = threadIdx.x & 63;
  int wr = (wid>>1)*64, wc = (wid&1)*64;
  int lrow = lane & 15;
  int lk   = (lane >> 4) * 8;
  long aoff = (long)(bm + wr + lrow)*lda + lk;
  long boff = (long)(bn + wc + lrow)*ldb + lk;
  f32x4 acc[4][4] = {};
  for (int k0=0; k0<K; k0+=32){
    bf16x8 ah[4], bh[4], al[4], bl[4];
    #pragma unroll
    for (int i=0;i<4;i++){
      ah[i] = *(const bf16x8*)(Ah + aoff + (long)(i*16)*lda + k0);
      bh[i] = *(const bf16x8*)(Wh + boff + (long)(i*16)*ldb + k0);
      if (AS==2) al[i] = *(const bf16x8*)(Al + aoff + (long)(i*16)*lda + k0);
      bl[i] = *(const bf16x8*)(Wl + boff + (long)(i*16)*ldb + k0);
    }
    #pragma unroll
    for (int i=0;i<4;i++)
      #pragma unroll
      for (int j=0;j<4;j++){
        acc[i][j] = __builtin_amdgcn_mfma_f32_16x16x32_bf16(ah[i], bh[j], acc[i][j], 0,0,0);
        acc[i][j] = __builtin_amdgcn_mfma_f32_16x16x32_bf16(ah[i], bl[j], acc[i][j], 0,0,0);
        if (AS==2) acc[i][j] = __builtin_amdgcn_mfma_f32_16x16x32_bf16(al[i], bh[j], acc[i][j], 0,0,0);
      }
  }
  int orow0 = bm + wr + (lane>>4)*4;
  int ocol0 = bn + wc + (lane&15);
  #pragma unroll
  for (int i=0;i<4;i++){
    #pragma unroll
    for (int j=0;j<4;j++){
      int col = ocol0 + j*16;
      float bv = bias ? bias[col] : 0.f;
      #pragma unroll
      for (int r=0;r<4;r++){
        int row = orow0 + i*16 + r;
        float v = acc[i][j][r] + bv;
        long idx = (long)row*ldc + col;
        if (Cf){
          if (accf) v += Cf[idx];
          Cf[idx] = v;
        } else {
          us h = f2bf(v);
          Chi[idx] = h;
          if (Clo) Clo[idx] = f2bf(v - bf2f(h));
        }
      }
    }
  }
}

// ------- wide variant: 1024 threads, 128 x 512 tile (N fixed 512) — A fetched once -------
template<int AS>
__global__ __launch_bounds__(1024) void gemm_msw_k(
    const us* __restrict__ Ah, const us* __restrict__ Al,
    const us* __restrict__ Wh, const us* __restrict__ Wl,
    float* __restrict__ Cf, us* __restrict__ Chi, us* __restrict__ Clo,
    const float* __restrict__ bias,
    int K, int lda, int ldb, int ldc)
{
  int bm = blockIdx.x*128;
  int wid = threadIdx.x >> 6, lane = threadIdx.x & 63;
  int wr = (wid>>3)*64, wc = (wid&7)*64;
  int lrow = lane & 15;
  int lk   = (lane >> 4) * 8;
  long aoff = (long)(bm + wr + lrow)*lda + lk;
  long boff = (long)(wc + lrow)*ldb + lk;
  f32x4 acc[4][4] = {};
  for (int k0=0; k0<K; k0+=32){
    bf16x8 ah[4], bh[4], al[4], bl[4];
    #pragma unroll
    for (int i=0;i<4;i++){
      ah[i] = *(const bf16x8*)(Ah + aoff + (long)(i*16)*lda + k0);
      bh[i] = *(const bf16x8*)(Wh + boff + (long)(i*16)*ldb + k0);
      if (AS==2) al[i] = *(const bf16x8*)(Al + aoff + (long)(i*16)*lda + k0);
      bl[i] = *(const bf16x8*)(Wl + boff + (long)(i*16)*ldb + k0);
    }
    #pragma unroll
    for (int i=0;i<4;i++)
      #pragma unroll
      for (int j=0;j<4;j++){
        acc[i][j] = __builtin_amdgcn_mfma_f32_16x16x32_bf16(ah[i], bh[j], acc[i][j], 0,0,0);
        acc[i][j] = __builtin_amdgcn_mfma_f32_16x16x32_bf16(ah[i], bl[j], acc[i][j], 0,0,0);
        if (AS==2) acc[i][j] = __builtin_amdgcn_mfma_f32_16x16x32_bf16(al[i], bh[j], acc[i][j], 0,0,0);
      }
  }
  int orow0 = bm + wr + (lane>>4)*4;
  int ocol0 = wc + (lane&15);
  #pragma unroll
  for (int i=0;i<4;i++){
    #pragma unroll
    for (int j=0;j<4;j++){
      int col = ocol0 + j*16;
      float bv = bias ? bias[col] : 0.f;
      #pragma unroll
      for (int r=0;r<4;r++){
        int row = orow0 + i*16 + r;
        float v = acc[i][j][r] + bv;
        long idx = (long)row*ldc + col;
        if (Cf){
          Cf[idx] = v;
        } else {
          us h = f2bf(v);
          Chi[idx] = h;
          if (Clo) Clo[idx] = f2bf(v - bf2f(h));
        }
      }
    }
  }
}

// ------- scores[b][q][k] = scale * dot(qh[q,b,:], kh[k,b,:]) over E=512, fp32 -------
template<int LK>
__global__ __launch_bounds__(256) void attn_scores_k(const float* __restrict__ qh,
                                                     const float* __restrict__ kh,
                                                     float* __restrict__ sc, float scale){
  __shared__ float Qs[48][65];
  __shared__ float Ks[LK][65];
  int b = blockIdx.x, tid = threadIdx.x;
  constexpr int NOUT = 48*LK;
  constexpr int NC = (NOUT + 255)/256;
  float acc[NC] = {};
  for (int e0=0;e0<512;e0+=64){
    for (int i=tid;i<48*64;i+=256){ int q=i>>6, e=i&63; Qs[q][e] = qh[((long)(q*512)+b)*512 + e0+e]; }
    for (int i=tid;i<LK*64;i+=256){ int k=i>>6, e=i&63; Ks[k][e] = kh[((long)(k*512)+b)*512 + e0+e]; }
    __syncthreads();
    #pragma unroll
    for (int cch=0;cch<NC;cch++){
      int oi = tid + cch*256;
      if (oi < NOUT){
        int q = oi / LK, k = oi % LK;
        float s = 0.f;
        #pragma unroll 8
        for (int e=0;e<64;e++) s += Qs[q][e]*Ks[k][e];
        acc[cch] += s;
      }
    }
    __syncthreads();
  }
  #pragma unroll
  for (int cch=0;cch<NC;cch++){
    int oi = tid + cch*256;
    if (oi < NOUT){
      int q = oi / LK, k = oi % LK;
      sc[((long)b*48 + q)*LK + k] = acc[cch]*scale;
    }
  }
}

// ---------------- row softmax (L small) ----------------
__global__ void softmax_rows_k(float* __restrict__ sc, int rows, int L){
  int r = blockIdx.x*blockDim.x + threadIdx.x;
  if (r>=rows) return;
  float* p = sc + (long)r*L;
  float m = -1e30f;
  for (int l=0;l<L;l++) m = fmaxf(m, p[l]);
  float s = 0.f;
  for (int l=0;l<L;l++){ float e = expf(p[l]-m); p[l]=e; s+=e; }
  float inv = 1.f/s;
  for (int l=0;l<L;l++) p[l]*=inv;
}

// ------- o[q][b][e] = sum_k attn[b][q][k]*vh[k][b][e]  (fp32 v, bf16 hi/lo out) -------
template<int LK>
__global__ __launch_bounds__(256) void attn_av_k(const float* __restrict__ at, const float* __restrict__ vh,
                                                 us* __restrict__ o_hi, us* __restrict__ o_lo){
  __shared__ float As[48][LK+1];
  int b = blockIdx.x;
  int e = blockIdx.y*256 + threadIdx.x;
  for (int i=threadIdx.x;i<48*LK;i+=256){ int q=i/LK, k=i%LK; As[q][k] = at[((long)b*48+q)*LK + k]; }
  __syncthreads();
  float acc[48];
  #pragma unroll
  for (int q=0;q<48;q++) acc[q]=0.f;
  for (int k=0;k<LK;k++){
    float v = vh[((long)(k*512)+b)*512 + e];
    #pragma unroll
    for (int q=0;q<48;q++) acc[q] += As[q][k]*v;
  }
  #pragma unroll
  for (int q=0;q<48;q++){
    long idx = ((long)(q*512)+b)*512 + e;
    us hh = f2bf(acc[q]);
    o_hi[idx] = hh;
    o_lo[idx] = f2bf(acc[q] - bf2f(hh));
  }
}

// ------- exact 1.5-entmax via bisection; logits row (t,b) -> out[b][t][:] -------
__global__ void entmax_k(const float* __restrict__ logits, float* __restrict__ out){
  int wid = (blockIdx.x*blockDim.x + threadIdx.x)>>6;
  int lane = threadIdx.x & 63;
  if (wid >= 24576) return;
  const float* x = logits + (long)wid*128;
  float a = x[lane]*0.5f;
  float b2 = x[lane+64]*0.5f;
  float m = fmaxf(a,b2);
  #pragma unroll
  for (int off=32;off;off>>=1) m = fmaxf(m, __shfl_xor(m, off));
  a -= m; b2 -= m;
  float lo = -1.f, hi = 0.f;
  for (int it=0; it<32; ++it){
    float mid = 0.5f*(lo+hi);
    float va = fmaxf(a-mid,0.f), vb = fmaxf(b2-mid,0.f);
    float s = va*va + vb*vb;
    #pragma unroll
    for (int off=32;off;off>>=1) s += __shfl_xor(s, off);
    if (s >= 1.f) lo = mid; else hi = mid;
  }
  float tau = 0.5f*(lo+hi);
  int t = wid >> 9;
  int b = wid & 511;
  float* o = out + ((long)b*48 + t)*128;
  float va = fmaxf(a-tau,0.f), vb = fmaxf(b2-tau,0.f);
  o[lane] = va*va;
  o[lane+64] = vb*vb;
}

extern "C" void kernel_launch(void* const* d_in, const int* in_sizes, int n_in,
                              void* d_out, int out_size, void* d_ws, size_t ws_size,
                              hipStream_t stream) {
  const int*   li        = (const int*)  d_in[0];
  const float* char_seq  = (const float*)d_in[1];
  const float* tagset    = (const float*)d_in[2];
  const float* labels    = (const float*)d_in[3];
  const float* lang_emb  = (const float*)d_in[4];
  const float* c_wih_f   = (const float*)d_in[5];
  const float* c_whh_f   = (const float*)d_in[6];
  const float* c_b_f     = (const float*)d_in[7];
  const float* c_wih_b   = (const float*)d_in[8];
  const float* c_whh_b   = (const float*)d_in[9];
  const float* c_b_b     = (const float*)d_in[10];
  const float* t_wih_f   = (const float*)d_in[11];
  const float* t_whh_f   = (const float*)d_in[12];
  const float* t_b_f     = (const float*)d_in[13];
  const float* t_wih_b   = (const float*)d_in[14];
  const float* t_whh_b   = (const float*)d_in[15];
  const float* t_b_b     = (const float*)d_in[16];
  const float* cell_wih  = (const float*)d_in[17];
  const float* cell_whh  = (const float*)d_in[18];
  const float* cell_b    = (const float*)d_in[19];
  const float* c_in_w    = (const float*)d_in[20];
  const float* c_in_b    = (const float*)d_in[21];
  const float* c_out_w   = (const float*)d_in[22];
  const float* c_out_b   = (const float*)d_in[23];
  const float* t_in_w    = (const float*)d_in[24];
  const float* t_in_b    = (const float*)d_in[25];
  const float* t_out_w   = (const float*)d_in[26];
  const float* t_out_b   = (const float*)d_in[27];
  const float* fc_w      = (const float*)d_in[28];
  const float* fc_b      = (const float*)d_in[29];
  (void)n_in; (void)in_sizes; (void)out_size;

  float* wsp = (float*)d_ws;
  long off = 0;
  auto alloc = [&](long n){ float* p = wsp + off; off += n; return p; };
  auto alloc_us = [&](long n_us){ return (us*)alloc((n_us+1)/2); };

  float* emb = alloc(32768);
  unsigned* hpkA = (unsigned*)alloc(262144);   // packed h [512][512] u32
  unsigned* hpkB = (unsigned*)alloc(262144);
  float* dec_c = alloc(262144);
  unsigned* hbpkA = (unsigned*)alloc(131072);  // packed h [512][256] u32 (bwd dirs)
  unsigned* hbpkB = (unsigned*)alloc(131072);
  float* logits = alloc(3145728);
  // permuted scan weights [4H][KH+KX]
  us* wcF_hi = alloc_us(458752); us* wcF_lo = alloc_us(458752);   // char 1024x448
  us* wcB_hi = alloc_us(458752); us* wcB_lo = alloc_us(458752);
  us* wtF_hi = alloc_us(393216); us* wtF_lo = alloc_us(393216);   // tag 1024x384
  us* wtB_hi = alloc_us(393216); us* wtB_lo = alloc_us(393216);
  us* wd_hi  = alloc_us(1310720); us* wd_lo = alloc_us(1310720);  // dec 2048x640
  // attn weight splits
  us* cinw_hi  = alloc_us(786432); us* cinw_lo  = alloc_us(786432);
  us* coutw_hi = alloc_us(262144); us* coutw_lo = alloc_us(262144);
  us* tinw_hi  = alloc_us(786432); us* tinw_lo  = alloc_us(786432);
  us* toutw_hi = alloc_us(262144); us* toutw_lo = alloc_us(262144);
  us* fcw_hi   = alloc_us(131072); us* fcw_lo   = alloc_us(131072);
  us* labels_hi= alloc_us(3145728);us* labels_lo= alloc_us(3145728);
  us* chout_hi = alloc_us(12582912);
  us* tgout_hi = alloc_us(4194304);
  us* hs_hi    = alloc_us(12582912);
  unsigned* cnts = (unsigned*)alloc(4);
  float* arena = alloc(26345472);
  long needed_bytes = off * 4;
  if ((long)ws_size < needed_bytes) {
    hipLaunchKernelGGL(zero_k, dim3(64), dim3(256), 0, stream, (float*)d_out, (long)128);
    return;
  }

  // arena overlays (phases strictly sequential)
  us* cs_hi = (us*)arena;
  us* cs_lo = (us*)(arena + 2359296);
  us* ts_hi = (us*)arena;
  us* ts_lo = (us*)(arena + 524288);
  float* qh = arena;
  float* kh = arena + 12582912;
  float* vh = qh;
  us* opv_hi = (us*)(arena + 12582912);
  us* opv_lo = (us*)(arena + 18874368);
  us* ca_hi  = (us*)arena;
  us* ca_lo  = (us*)(arena + 6291456);
  float* sc_s = arena + 25165824;

  auto SPLIT = [&](const float* src, us* hi, us* lo, long n){
    hipLaunchKernelGGL(split_k, dim3(256), dim3(256), 0, stream, src, hi, lo, n);
  };
  auto PERM = [&](const float* Whh, const float* Wih, us* hi, us* lo, int H, int KH, int KX){
    hipLaunchKernelGGL(permsplit_k, dim3(1024), dim3(256), 0, stream, Whh, Wih, hi, lo, H, KH, KX);
  };
  auto MS = [&](int AS, const us* Ah, const us* Al, const us* Wh, const us* Wl,
                float* Cf, us* Chi, us* Clo, const float* bias,
                int M,int N,int K,int lda,int ldb,int ldc,int accf){
    dim3 gr(N/128, M/128);
    if (AS==1) hipLaunchKernelGGL((gemm_ms_k<1>), gr, dim3(256), 0, stream,
                                  Ah,Al,Wh,Wl,Cf,Chi,Clo,bias,M,N,K,lda,ldb,ldc,accf);
    else       hipLaunchKernelGGL((gemm_ms_k<2>), gr, dim3(256), 0, stream,
                                  Ah,Al,Wh,Wl,Cf,Chi,Clo,bias,M,N,K,lda,ldb,ldc,accf);
  };
  auto MSW = [&](int AS, const us* Ah, const us* Al, const us* Wh, const us* Wl,
                 float* Cf, us* Chi, us* Clo, const float* bias,
                 int M,int K,int lda,int ldb,int ldc){
    dim3 gr(M/128);
    if (AS==1) hipLaunchKernelGGL((gemm_msw_k<1>), gr, dim3(1024), 0, stream,
                                  Ah,Al,Wh,Wl,Cf,Chi,Clo,bias,K,lda,ldb,ldc);
    else       hipLaunchKernelGGL((gemm_msw_k<2>), gr, dim3(1024), 0, stream,
                                  Ah,Al,Wh,Wl,Cf,Chi,Clo,bias,K,lda,ldb,ldc);
  };

  // ---- prep: weight permute/splits ----
  PERM(c_whh_f, c_wih_f, wcF_hi, wcF_lo, 256, 256, 192);
  PERM(c_whh_b, c_wih_b, wcB_hi, wcB_lo, 256, 256, 192);
  PERM(t_whh_f, t_wih_f, wtF_hi, wtF_lo, 256, 256, 128);
  PERM(t_whh_b, t_wih_b, wtB_hi, wtB_lo, 256, 256, 128);
  PERM(cell_whh, cell_wih, wd_hi, wd_lo, 512, 512, 128);
  SPLIT(c_in_w,  cinw_hi,  cinw_lo,  786432);
  SPLIT(c_out_w, coutw_hi, coutw_lo, 262144);
  SPLIT(t_in_w,  tinw_hi,  tinw_lo,  786432);
  SPLIT(t_out_w, toutw_hi, toutw_lo, 262144);
  SPLIT(fc_w,    fcw_hi,   fcw_lo,   131072);
  SPLIT(labels,  labels_hi,labels_lo,3145728);

  // ---- emb + zero init states/counters ----
  hipLaunchKernelGGL(emb_k, dim3(512), dim3(64), 0, stream, li, lang_emb, emb);
  hipLaunchKernelGGL(zero_k, dim3(256), dim3(256), 0, stream, (float*)hpkA, (long)262144);
  hipLaunchKernelGGL(zero_k, dim3(128), dim3(256), 0, stream, (float*)hbpkA, (long)131072);
  hipLaunchKernelGGL(zero_k, dim3(1), dim3(64), 0, stream, (float*)cnts, (long)4);

  // ---- char phase: concat inputs, then persistent fwd+bwd scan ----
  {
    long tot = 512l*48*192;
    hipLaunchKernelGGL(build_concat_k, dim3((unsigned)((tot+255)/256)), dim3(256), 0, stream,
                       char_seq, emb, cs_hi, cs_lo, 48, 128, 64, tot);
  }
  {
    ScanDir F, Bd;
    F.Whi=wcF_hi; F.Wlo=wcF_lo; F.bias=c_b_f;
    F.Xh=cs_hi; F.Xl=cs_lo; F.ldx=9216; F.xrev=0; F.skip_x_t0=0;
    F.hpkA=hpkA; F.hpkB=hpkB; F.ldw=512;
    F.c0=nullptr; F.cfin=dec_c;
    F.out=chout_hi; F.ldo=512; F.otstride=262144; F.H=256; F.nWG=64;
    Bd.Whi=wcB_hi; Bd.Wlo=wcB_lo; Bd.bias=c_b_b;
    Bd.Xh=cs_hi; Bd.Xl=cs_lo; Bd.ldx=9216; Bd.xrev=1; Bd.skip_x_t0=0;
    Bd.hpkA=hbpkA; Bd.hpkB=hbpkB; Bd.ldw=256;
    Bd.c0=nullptr; Bd.cfin=nullptr;
    Bd.out=chout_hi+256; Bd.ldo=512; Bd.otstride=262144; Bd.H=256; Bd.nWG=64;
    hipLaunchKernelGGL((scan_k<256,192>), dim3(128), dim3(256), 0, stream, F, Bd, 2, 48, 128, cnts+0);
  }

  // ---- tag phase ----
  hipLaunchKernelGGL(zero_k, dim3(128), dim3(256), 0, stream, (float*)hbpkA, (long)131072);
  {
    long tot = 512l*16*128;
    hipLaunchKernelGGL(build_concat_k, dim3((unsigned)((tot+255)/256)), dim3(256), 0, stream,
                       tagset, emb, ts_hi, ts_lo, 16, 64, 64, tot);
  }
  {
    ScanDir F, Bd;
    F.Whi=wtF_hi; F.Wlo=wtF_lo; F.bias=t_b_f;
    F.Xh=ts_hi; F.Xl=ts_lo; F.ldx=2048; F.xrev=0; F.skip_x_t0=0;
    F.hpkA=hpkA+256; F.hpkB=hpkB+256; F.ldw=512;
    F.c0=nullptr; F.cfin=dec_c+256;
    F.out=tgout_hi; F.ldo=512; F.otstride=262144; F.H=256; F.nWG=64;
    Bd.Whi=wtB_hi; Bd.Wlo=wtB_lo; Bd.bias=t_b_b;
    Bd.Xh=ts_hi; Bd.Xl=ts_lo; Bd.ldx=2048; Bd.xrev=1; Bd.skip_x_t0=0;
    Bd.hpkA=hbpkA; Bd.hpkB=hbpkB; Bd.ldw=256;
    Bd.c0=nullptr; Bd.cfin=nullptr;
    Bd.out=tgout_hi+256; Bd.ldo=512; Bd.otstride=262144; Bd.H=256; Bd.nWG=64;
    hipLaunchKernelGGL((scan_k<256,128>), dim3(128), dim3(256), 0, stream, F, Bd, 2, 16, 128, cnts+1);
  }

  // ---- decoder (h0 in hpkA, c0 in dec_c) ----
  {
    ScanDir D;
    D.Whi=wd_hi; D.Wlo=wd_lo; D.bias=cell_b;
    D.Xh=labels_hi; D.Xl=labels_lo; D.ldx=6144; D.xrev=0; D.skip_x_t0=1;
    D.hpkA=hpkA; D.hpkB=hpkB; D.ldw=512;
    D.c0=dec_c; D.cfin=nullptr;
    D.out=hs_hi; D.ldo=512; D.otstride=262144; D.H=512; D.nWG=128;
    hipLaunchKernelGGL((scan_k<512,128>), dim3(128), dim3(256), 0, stream, D, D, 1, 48, 128, cnts+2);
  }

  const float scale = 0.044194173824159216f; // 1/sqrt(512)

  // ---- attentions + fc ----
  for (int which=0; which<2; ++which){
    const float* in_b  = which ? t_in_b  : c_in_b;
    const float* out_b = which ? t_out_b : c_out_b;
    const us* inw_hi = which ? tinw_hi : cinw_hi;
    const us* inw_lo = which ? tinw_lo : cinw_lo;
    const us* outw_hi= which ? toutw_hi: coutw_hi;
    const us* outw_lo= which ? toutw_lo: coutw_lo;
    const us* src    = which ? tgout_hi: chout_hi;
    int Mkv = which ? 8192 : 24576;
    int LK  = which ? 16 : 48;
    MSW(1, hs_hi, nullptr, inw_hi, inw_lo, qh, nullptr, nullptr, in_b,
        24576,512, 512,512,512);
    MSW(1, src, nullptr, inw_hi + (long)512*512, inw_lo + (long)512*512, kh, nullptr, nullptr, in_b+512,
        Mkv,512, 512,512,512);
    if (LK==48) hipLaunchKernelGGL((attn_scores_k<48>), dim3(512), dim3(256), 0, stream, qh, kh, sc_s, scale);
    else        hipLaunchKernelGGL((attn_scores_k<16>), dim3(512), dim3(256), 0, stream, qh, kh, sc_s, scale);
    hipLaunchKernelGGL(softmax_rows_k, dim3((24576+255)/256), dim3(256), 0, stream, sc_s, 24576, LK);
    MSW(1, src, nullptr, inw_hi + (long)1024*512, inw_lo + (long)1024*512, vh, nullptr, nullptr, in_b+1024,
        Mkv,512, 512,512,512);
    if (LK==48) hipLaunchKernelGGL((attn_av_k<48>), dim3(512,2), dim3(256), 0, stream, sc_s, vh, opv_hi, opv_lo);
    else        hipLaunchKernelGGL((attn_av_k<16>), dim3(512,2), dim3(256), 0, stream, sc_s, vh, opv_hi, opv_lo);
    MSW(2, opv_hi, opv_lo, outw_hi, outw_lo, nullptr, ca_hi, ca_lo, out_b,
        24576,512, 512,512,512);
    MS(2, ca_hi, ca_lo, fcw_hi + which*512, fcw_lo + which*512, logits, nullptr, nullptr,
       which ? nullptr : fc_b, 24576,128,512, 512,1024,128, which);
  }

  // ---- entmax 1.5 + transpose to [B, SC, 128] ----
  hipLaunchKernelGGL(entmax_k, dim3(6144), dim3(256), 0, stream, logits, (float*)d_out);
}

// Round 8
// 3643.262 us; speedup vs baseline: 1.3492x; 1.3492x over previous
//
#include <hip/hip_runtime.h>
#include <math.h>

using bf16x8 = __attribute__((ext_vector_type(8))) short;
using short16 = __attribute__((ext_vector_type(16))) short;
using f32x4  = __attribute__((ext_vector_type(4))) float;
typedef unsigned short us;
typedef unsigned long long u64;

__device__ __forceinline__ float sigf(float x){ return 1.f/(1.f+expf(-x)); }

__device__ __forceinline__ us f2bf(float x){
  union { float f; unsigned u; } v; v.f = x;
  unsigned r = v.u + 0x7FFF + ((v.u>>16)&1);
  return (us)(r>>16);
}
__device__ __forceinline__ float bf2f(us h){
  union { unsigned u; float f; } v; v.u = ((unsigned)h)<<16; return v.f;
}

__device__ __forceinline__ void mfma3(f32x4& acc, bf16x8 ah, bf16x8 al, bf16x8 bh, bf16x8 bl){
  acc = __builtin_amdgcn_mfma_f32_16x16x32_bf16(ah, bh, acc, 0,0,0);
  acc = __builtin_amdgcn_mfma_f32_16x16x32_bf16(ah, bl, acc, 0,0,0);
  acc = __builtin_amdgcn_mfma_f32_16x16x32_bf16(al, bh, acc, 0,0,0);
}

// hierarchical fence-free grid barrier (h exchanged via sc1/MALL atomics).
// cx: 8 padded per-XCD counters (stride 32 u32); cg: global counter.
// Correct for ANY partition of 256 WGs into 8 groups of 32 via blockIdx&7.
__device__ __forceinline__ void grid_sync2(unsigned* cx, unsigned* cg, int xcd, unsigned tgt){
  __syncthreads();
  if (threadIdx.x == 0){
    unsigned old = __hip_atomic_fetch_add(cx + xcd*32, 1u, __ATOMIC_RELAXED, __HIP_MEMORY_SCOPE_AGENT);
    if ((old & 31u) == 31u)
      __hip_atomic_fetch_add(cg, 1u, __ATOMIC_RELAXED, __HIP_MEMORY_SCOPE_AGENT);
    while (__hip_atomic_load(cg, __ATOMIC_RELAXED, __HIP_MEMORY_SCOPE_AGENT) < tgt)
      __builtin_amdgcn_s_sleep(1);
  }
  __syncthreads();
}

// ---------------- zero fill ----------------
__global__ void zero_k(float* __restrict__ p, long n){
  long i = (long)blockIdx.x*blockDim.x + threadIdx.x;
  long stride = (long)gridDim.x*blockDim.x;
  for (; i<n; i+=stride) p[i] = 0.f;
}

// ---------------- fp32 -> bf16 hi + lo ----------------
__global__ void split_k(const float* __restrict__ in, us* __restrict__ hi,
                        us* __restrict__ lo, long n){
  long i = (long)blockIdx.x*blockDim.x + threadIdx.x;
  long stride = (long)gridDim.x*blockDim.x;
  for (; i<n; i+=stride){
    float x = in[i];
    us h = f2bf(x);
    hi[i] = h;
    lo[i] = f2bf(x - bf2f(h));
  }
}

// ---- time-major transpose + split: out[s][b][d] = in[b][s][d] ----
__global__ void tsplit_k(const float* __restrict__ in, us* __restrict__ hi,
                         us* __restrict__ lo, int B, int S, int D){
  long total = (long)B*S*D;
  long i = (long)blockIdx.x*blockDim.x + threadIdx.x;
  long stride = (long)gridDim.x*blockDim.x;
  for (; i<total; i+=stride){
    int d = (int)(i % D);
    long r = i / D;
    int b = (int)(r % B);
    int s = (int)(r / B);
    float v = in[((long)b*S + s)*D + d];
    us h = f2bf(v);
    hi[i] = h;
    lo[i] = f2bf(v - bf2f(h));
  }
}

// ---- permute+split scan weights: out[nb*64 + g*16 + jl][c] = (c<KH ? Whh : Wih)[g*H + nb*16 + jl][...]
__global__ void permsplit_k(const float* __restrict__ Whh, const float* __restrict__ Wih,
                            us* __restrict__ hi, us* __restrict__ lo, int H, int KH, int KX){
  int KHX = KH + KX;
  long total = (long)4*H*KHX;
  long i = (long)blockIdx.x*blockDim.x + threadIdx.x;
  long stride = (long)gridDim.x*blockDim.x;
  for (; i<total; i+=stride){
    int c = (int)(i % KHX);
    int r = (int)(i / KHX);
    int nb = r >> 6, rem = r & 63, g = rem >> 4, jl = rem & 15;
    int in_row = g*H + nb*16 + jl;
    float v = (c < KH) ? Whh[(long)in_row*KH + c] : Wih[(long)in_row*KX + (c-KH)];
    us h = f2bf(v);
    hi[i] = h;
    lo[i] = f2bf(v - bf2f(h));
  }
}

// ---------------- emb[b][d] = lang_embeds[ li[li[b]] ][d] ----------------
__global__ void emb_k(const int* __restrict__ li, const float* __restrict__ le, float* __restrict__ emb){
  int b = blockIdx.x, d = threadIdx.x;
  int idx = li[li[b]];
  emb[b*64+d] = le[idx*64+d];
}

// ------- time-major concat: out[s][b][0:D1]=seq[b][s], [D1:D)=emb[b]  (bf16 hi/lo) -------
__global__ void build_concat_k(const float* __restrict__ seq, const float* __restrict__ emb,
                               us* __restrict__ hi, us* __restrict__ lo,
                               int B, int S, int D1, int D2, long total){
  long i = (long)blockIdx.x*blockDim.x + threadIdx.x;
  if (i>=total) return;
  int D = D1+D2;
  int d = (int)(i % D);
  long r = i / D;
  int b = (int)(r % B);
  int s = (int)(r / B);
  float v = (d<D1) ? seq[((long)b*S+s)*D1 + d] : emb[b*64 + (d-D1)];
  us h = f2bf(v);
  hi[i] = h;
  lo[i] = f2bf(v - bf2f(h));
}

// ======================= persistent LSTM scan =======================
// 256 WGs of 256 threads; each WG owns 64 batch rows x 16 hidden cols (nb).
// XCD-aware swizzle: blockIdx&7 picks the XCD (round-robin dispatch), so WGs
// sharing an X/h row-group co-locate on one XCD -> X is fetched once per XCD.
// h state: packed u32 (hi|lo<<16) exchanged via sc1/MALL relaxed atomics.
struct ScanDir {
  const us* Whi; const us* Wlo;   // [4H][KH+KX], gate-interleaved permuted rows
  const float* bias;              // [4H] original layout
  const us* Xh; const us* Xl;     // time-major [S][512][KX]
  int xrev; int skip_x_t0;
  unsigned* hpkA; unsigned* hpkB; int ldw;   // packed h double buffer (pre-offset by col)
  const float* c0; float* cfin;   // c init/final (ld 512, pre-offset)
  us* out; int ldo; long otstride;
  int H;
};

template<int KH, int KX>
__global__ __launch_bounds__(256) void scan_k(ScanDir d0, ScanDir d1, int ndir,
                                              int nsteps, unsigned* cx, unsigned* cg)
{
  constexpr int KHX = KH + KX;
  constexpr bool XL = (KHX <= 512);       // whole W-hi slice fits 64KB LDS?
  constexpr int LDSC = XL ? KHX : KH;
  __shared__ us Wsh[64*LDSC];
  int xcd = blockIdx.x & 7;
  int lwg = xcd*32 + (blockIdx.x >> 3);   // XCD-contiguous logical WG id
  ScanDir d = d0;
  if (ndir == 2 && lwg >= 128){ d = d1; lwg -= 128; }
  int nnb = d.H >> 4;
  int mb = lwg / nnb;                     // 64-row batch group (0..7)
  int nb = lwg % nnb;
  int lane = threadIdx.x & 63, w = threadIdx.x >> 6;
  int lrow = lane & 15, klane = (lane >> 4) * 8;
  int rowbase = mb*64 + w*16;             // this wave's 16 batch rows
  int jj = nb*16 + lrow;

  // stage hi-limb W slice into LDS, XOR-swizzled
  const us* wsrc = d.Whi + (long)(nb*64)*KHX;
  for (int ci = threadIdx.x; ci < 64*(LDSC/8); ci += 256){
    int r = ci / (LDSC/8), cb = ci % (LDSC/8);
    bf16x8 v = *(const bf16x8*)(wsrc + (long)r*KHX + cb*8);
    int byte = r*(LDSC*2) + cb*16;
    byte ^= (r & 7) << 4;
    *(bf16x8*)((char*)Wsh + byte) = v;
  }
  float bg[4];
  #pragma unroll
  for (int g=0; g<4; ++g) bg[g] = d.bias[g*d.H + jj];
  float creg[4];
  #pragma unroll
  for (int r=0;r<4;r++){
    int row = rowbase + (lane>>4)*4 + r;
    creg[r] = d.c0 ? d.c0[(long)row*512 + jj] : 0.f;
  }
  __syncthreads();

  const us* Wlo_base = d.Wlo + (long)(nb*64)*KHX;

  for (int t=0; t<nsteps; ++t){
    const unsigned* Rpk = (t&1) ? d.hpkB : d.hpkA;
    unsigned*       Wpk = (t&1) ? d.hpkA : d.hpkB;
    int teff = d.xrev ? (nsteps-1-t) : t;
    f32x4 acc[4] = {};
    // recurrent part: gates += h @ W_hh'   (h via sc1/MALL atomic loads)
    for (int k0=0; k0<KH; k0+=32){
      const unsigned* hp = Rpk + (long)(rowbase + lrow)*d.ldw + k0 + klane;
      union { u64 q[4]; short16 s; } uu;
      uu.q[0] = __hip_atomic_load((const u64*)(hp+0), __ATOMIC_RELAXED, __HIP_MEMORY_SCOPE_AGENT);
      uu.q[1] = __hip_atomic_load((const u64*)(hp+2), __ATOMIC_RELAXED, __HIP_MEMORY_SCOPE_AGENT);
      uu.q[2] = __hip_atomic_load((const u64*)(hp+4), __ATOMIC_RELAXED, __HIP_MEMORY_SCOPE_AGENT);
      uu.q[3] = __hip_atomic_load((const u64*)(hp+6), __ATOMIC_RELAXED, __HIP_MEMORY_SCOPE_AGENT);
      bf16x8 ah = __builtin_shufflevector(uu.s, uu.s, 0,2,4,6,8,10,12,14);
      bf16x8 al = __builtin_shufflevector(uu.s, uu.s, 1,3,5,7,9,11,13,15);
      #pragma unroll
      for (int nf=0; nf<4; nf++){
        int rB = nf*16 + lrow;
        int byte = rB*(LDSC*2) + (k0 + klane)*2;
        byte ^= (rB & 7) << 4;
        bf16x8 bh = *(const bf16x8*)((const char*)Wsh + byte);
        bf16x8 bl = *(const bf16x8*)(Wlo_base + (long)rB*KHX + k0 + klane);
        mfma3(acc[nf], ah, al, bh, bl);
      }
    }
    // input part: gates += x_t @ W_ih'   (time-major X: contiguous per step)
    if (!(d.skip_x_t0 && t==0)){
      long xrow = ((long)teff*512 + rowbase + lrow)*KX;
      for (int k0=0; k0<KX; k0+=32){
        bf16x8 ah = *(const bf16x8*)(d.Xh + xrow + k0 + klane);
        bf16x8 al = *(const bf16x8*)(d.Xl + xrow + k0 + klane);
        #pragma unroll
        for (int nf=0; nf<4; nf++){
          int rB = nf*16 + lrow;
          bf16x8 bh;
          if (XL){
            int byte = rB*(LDSC*2) + (KH + k0 + klane)*2;
            byte ^= (rB & 7) << 4;
            bh = *(const bf16x8*)((const char*)Wsh + byte);
          } else {
            bh = *(const bf16x8*)(d.Whi + (long)(nb*64 + rB)*KHX + KH + k0 + klane);
          }
          bf16x8 bl = *(const bf16x8*)(Wlo_base + (long)rB*KHX + KH + k0 + klane);
          mfma3(acc[nf], ah, al, bh, bl);
        }
      }
    }
    // activation (gate g == n-fragment nf thanks to permuted W rows)
    int last = (t == nsteps-1);
    #pragma unroll
    for (int r=0;r<4;r++){
      int row = rowbase + (lane>>4)*4 + r;
      float gi = acc[0][r] + bg[0];
      float gf = acc[1][r] + bg[1];
      float gg = acc[2][r] + bg[2];
      float go = acc[3][r] + bg[3];
      float cn = sigf(gf)*creg[r] + sigf(gi)*tanhf(gg);
      float hn = sigf(go)*tanhf(cn);
      creg[r] = cn;
      us hh = f2bf(hn);
      unsigned pk = (unsigned)hh | ((unsigned)f2bf(hn - bf2f(hh)) << 16);
      __hip_atomic_store(Wpk + (long)row*d.ldw + jj, pk, __ATOMIC_RELAXED, __HIP_MEMORY_SCOPE_AGENT);
      d.out[(long)teff*d.otstride + (long)row*d.ldo + jj] = hh;
      if (last && d.cfin) d.cfin[(long)row*512 + jj] = cn;
    }
    if (t+1 < nsteps) grid_sync2(cx, cg, xcd, (unsigned)(8*(t+1)));
  }
}

// ------- split-bf16 MFMA GEMM (128x128 tile): C[M,N] = (Ah+Al) @ (Wh+Wl)^T (+bias) -------
template<int AS>
__global__ __launch_bounds__(256) void gemm_ms_k(
    const us* __restrict__ Ah, const us* __restrict__ Al,
    const us* __restrict__ Wh, const us* __restrict__ Wl,
    float* __restrict__ Cf, us* __restrict__ Chi, us* __restrict__ Clo,
    const float* __restrict__ bias,
    int M, int N, int K, int lda, int ldb, int ldc, int accf)
{
  int bm = blockIdx.y*128, bn = blockIdx.x*128;
  int wid = threadIdx.x >> 6, lane = threadIdx.x & 63;
  int wr = (wid>>1)*64, wc = (wid&1)*64;
  int lrow = lane & 15;
  int lk   = (lane >> 4) * 8;
  long aoff = (long)(bm + wr + lrow)*lda + lk;
  long boff = (long)(bn + wc + lrow)*ldb + lk;
  f32x4 acc[4][4] = {};
  for (int k0=0; k0<K; k0+=32){
    bf16x8 ah[4], bh[4], al[4], bl[4];
    #pragma unroll
    for (int i=0;i<4;i++){
      ah[i] = *(const bf16x8*)(Ah + aoff + (long)(i*16)*lda + k0);
      bh[i] = *(const bf16x8*)(Wh + boff + (long)(i*16)*ldb + k0);
      if (AS==2) al[i] = *(const bf16x8*)(Al + aoff + (long)(i*16)*lda + k0);
      bl[i] = *(const bf16x8*)(Wl + boff + (long)(i*16)*ldb + k0);
    }
    #pragma unroll
    for (int i=0;i<4;i++)
      #pragma unroll
      for (int j=0;j<4;j++){
        acc[i][j] = __builtin_amdgcn_mfma_f32_16x16x32_bf16(ah[i], bh[j], acc[i][j], 0,0,0);
        acc[i][j] = __builtin_amdgcn_mfma_f32_16x16x32_bf16(ah[i], bl[j], acc[i][j], 0,0,0);
        if (AS==2) acc[i][j] = __builtin_amdgcn_mfma_f32_16x16x32_bf16(al[i], bh[j], acc[i][j], 0,0,0);
      }
  }
  int orow0 = bm + wr + (lane>>4)*4;
  int ocol0 = bn + wc + (lane&15);
  #pragma unroll
  for (int i=0;i<4;i++){
    #pragma unroll
    for (int j=0;j<4;j++){
      int col = ocol0 + j*16;
      float bv = bias ? bias[col] : 0.f;
      #pragma unroll
      for (int r=0;r<4;r++){
        int row = orow0 + i*16 + r;
        float v = acc[i][j][r] + bv;
        long idx = (long)row*ldc + col;
        if (Cf){
          if (accf) v += Cf[idx];
          Cf[idx] = v;
        } else {
          us h = f2bf(v);
          Chi[idx] = h;
          if (Clo) Clo[idx] = f2bf(v - bf2f(h));
        }
      }
    }
  }
}

// ------- wide variant: 1024 threads, 128 x 512 tile (N fixed 512) — A fetched once -------
template<int AS>
__global__ __launch_bounds__(1024) void gemm_msw_k(
    const us* __restrict__ Ah, const us* __restrict__ Al,
    const us* __restrict__ Wh, const us* __restrict__ Wl,
    float* __restrict__ Cf, us* __restrict__ Chi, us* __restrict__ Clo,
    const float* __restrict__ bias,
    int K, int lda, int ldb, int ldc)
{
  int bm = blockIdx.x*128;
  int wid = threadIdx.x >> 6, lane = threadIdx.x & 63;
  int wr = (wid>>3)*64, wc = (wid&7)*64;
  int lrow = lane & 15;
  int lk   = (lane >> 4) * 8;
  long aoff = (long)(bm + wr + lrow)*lda + lk;
  long boff = (long)(wc + lrow)*ldb + lk;
  f32x4 acc[4][4] = {};
  for (int k0=0; k0<K; k0+=32){
    bf16x8 ah[4], bh[4], al[4], bl[4];
    #pragma unroll
    for (int i=0;i<4;i++){
      ah[i] = *(const bf16x8*)(Ah + aoff + (long)(i*16)*lda + k0);
      bh[i] = *(const bf16x8*)(Wh + boff + (long)(i*16)*ldb + k0);
      if (AS==2) al[i] = *(const bf16x8*)(Al + aoff + (long)(i*16)*lda + k0);
      bl[i] = *(const bf16x8*)(Wl + boff + (long)(i*16)*ldb + k0);
    }
    #pragma unroll
    for (int i=0;i<4;i++)
      #pragma unroll
      for (int j=0;j<4;j++){
        acc[i][j] = __builtin_amdgcn_mfma_f32_16x16x32_bf16(ah[i], bh[j], acc[i][j], 0,0,0);
        acc[i][j] = __builtin_amdgcn_mfma_f32_16x16x32_bf16(ah[i], bl[j], acc[i][j], 0,0,0);
        if (AS==2) acc[i][j] = __builtin_amdgcn_mfma_f32_16x16x32_bf16(al[i], bh[j], acc[i][j], 0,0,0);
      }
  }
  int orow0 = bm + wr + (lane>>4)*4;
  int ocol0 = wc + (lane&15);
  #pragma unroll
  for (int i=0;i<4;i++){
    #pragma unroll
    for (int j=0;j<4;j++){
      int col = ocol0 + j*16;
      float bv = bias ? bias[col] : 0.f;
      #pragma unroll
      for (int r=0;r<4;r++){
        int row = orow0 + i*16 + r;
        float v = acc[i][j][r] + bv;
        long idx = (long)row*ldc + col;
        if (Cf){
          Cf[idx] = v;
        } else {
          us h = f2bf(v);
          Chi[idx] = h;
          if (Clo) Clo[idx] = f2bf(v - bf2f(h));
        }
      }
    }
  }
}

// ------- scores[b][q][k] = scale * dot(qh[q,b,:], kh[k,b,:]) over E=512, fp32 -------
template<int LK>
__global__ __launch_bounds__(256) void attn_scores_k(const float* __restrict__ qh,
                                                     const float* __restrict__ kh,
                                                     float* __restrict__ sc, float scale){
  __shared__ float Qs[48][65];
  __shared__ float Ks[LK][65];
  int b = blockIdx.x, tid = threadIdx.x;
  constexpr int NOUT = 48*LK;
  constexpr int NC = (NOUT + 255)/256;
  float acc[NC] = {};
  for (int e0=0;e0<512;e0+=64){
    for (int i=tid;i<48*64;i+=256){ int q=i>>6, e=i&63; Qs[q][e] = qh[((long)(q*512)+b)*512 + e0+e]; }
    for (int i=tid;i<LK*64;i+=256){ int k=i>>6, e=i&63; Ks[k][e] = kh[((long)(k*512)+b)*512 + e0+e]; }
    __syncthreads();
    #pragma unroll
    for (int cch=0;cch<NC;cch++){
      int oi = tid + cch*256;
      if (oi < NOUT){
        int q = oi / LK, k = oi % LK;
        float s = 0.f;
        #pragma unroll 8
        for (int e=0;e<64;e++) s += Qs[q][e]*Ks[k][e];
        acc[cch] += s;
      }
    }
    __syncthreads();
  }
  #pragma unroll
  for (int cch=0;cch<NC;cch++){
    int oi = tid + cch*256;
    if (oi < NOUT){
      int q = oi / LK, k = oi % LK;
      sc[((long)b*48 + q)*LK + k] = acc[cch]*scale;
    }
  }
}

// ---------------- row softmax (L small) ----------------
__global__ void softmax_rows_k(float* __restrict__ sc, int rows, int L){
  int r = blockIdx.x*blockDim.x + threadIdx.x;
  if (r>=rows) return;
  float* p = sc + (long)r*L;
  float m = -1e30f;
  for (int l=0;l<L;l++) m = fmaxf(m, p[l]);
  float s = 0.f;
  for (int l=0;l<L;l++){ float e = expf(p[l]-m); p[l]=e; s+=e; }
  float inv = 1.f/s;
  for (int l=0;l<L;l++) p[l]*=inv;
}

// ------- o[q][b][e] = sum_k attn[b][q][k]*vh[k][b][e]  (fp32 v, bf16 hi/lo out) -------
template<int LK>
__global__ __launch_bounds__(256) void attn_av_k(const float* __restrict__ at, const float* __restrict__ vh,
                                                 us* __restrict__ o_hi, us* __restrict__ o_lo){
  __shared__ float As[48][LK+1];
  int b = blockIdx.x;
  int e = blockIdx.y*256 + threadIdx.x;
  for (int i=threadIdx.x;i<48*LK;i+=256){ int q=i/LK, k=i%LK; As[q][k] = at[((long)b*48+q)*LK + k]; }
  __syncthreads();
  float acc[48];
  #pragma unroll
  for (int q=0;q<48;q++) acc[q]=0.f;
  for (int k=0;k<LK;k++){
    float v = vh[((long)(k*512)+b)*512 + e];
    #pragma unroll
    for (int q=0;q<48;q++) acc[q] += As[q][k]*v;
  }
  #pragma unroll
  for (int q=0;q<48;q++){
    long idx = ((long)(q*512)+b)*512 + e;
    us hh = f2bf(acc[q]);
    o_hi[idx] = hh;
    o_lo[idx] = f2bf(acc[q] - bf2f(hh));
  }
}

// ------- exact 1.5-entmax via bisection; logits row (t,b) -> out[b][t][:] -------
__global__ void entmax_k(const float* __restrict__ logits, float* __restrict__ out){
  int wid = (blockIdx.x*blockDim.x + threadIdx.x)>>6;
  int lane = threadIdx.x & 63;
  if (wid >= 24576) return;
  const float* x = logits + (long)wid*128;
  float a = x[lane]*0.5f;
  float b2 = x[lane+64]*0.5f;
  float m = fmaxf(a,b2);
  #pragma unroll
  for (int off=32;off;off>>=1) m = fmaxf(m, __shfl_xor(m, off));
  a -= m; b2 -= m;
  float lo = -1.f, hi = 0.f;
  for (int it=0; it<32; ++it){
    float mid = 0.5f*(lo+hi);
    float va = fmaxf(a-mid,0.f), vb = fmaxf(b2-mid,0.f);
    float s = va*va + vb*vb;
    #pragma unroll
    for (int off=32;off;off>>=1) s += __shfl_xor(s, off);
    if (s >= 1.f) lo = mid; else hi = mid;
  }
  float tau = 0.5f*(lo+hi);
  int t = wid >> 9;
  int b = wid & 511;
  float* o = out + ((long)b*48 + t)*128;
  float va = fmaxf(a-tau,0.f), vb = fmaxf(b2-tau,0.f);
  o[lane] = va*va;
  o[lane+64] = vb*vb;
}

extern "C" void kernel_launch(void* const* d_in, const int* in_sizes, int n_in,
                              void* d_out, int out_size, void* d_ws, size_t ws_size,
                              hipStream_t stream) {
  const int*   li        = (const int*)  d_in[0];
  const float* char_seq  = (const float*)d_in[1];
  const float* tagset    = (const float*)d_in[2];
  const float* labels    = (const float*)d_in[3];
  const float* lang_emb  = (const float*)d_in[4];
  const float* c_wih_f   = (const float*)d_in[5];
  const float* c_whh_f   = (const float*)d_in[6];
  const float* c_b_f     = (const float*)d_in[7];
  const float* c_wih_b   = (const float*)d_in[8];
  const float* c_whh_b   = (const float*)d_in[9];
  const float* c_b_b     = (const float*)d_in[10];
  const float* t_wih_f   = (const float*)d_in[11];
  const float* t_whh_f   = (const float*)d_in[12];
  const float* t_b_f     = (const float*)d_in[13];
  const float* t_wih_b   = (const float*)d_in[14];
  const float* t_whh_b   = (const float*)d_in[15];
  const float* t_b_b     = (const float*)d_in[16];
  const float* cell_wih  = (const float*)d_in[17];
  const float* cell_whh  = (const float*)d_in[18];
  const float* cell_b    = (const float*)d_in[19];
  const float* c_in_w    = (const float*)d_in[20];
  const float* c_in_b    = (const float*)d_in[21];
  const float* c_out_w   = (const float*)d_in[22];
  const float* c_out_b   = (const float*)d_in[23];
  const float* t_in_w    = (const float*)d_in[24];
  const float* t_in_b    = (const float*)d_in[25];
  const float* t_out_w   = (const float*)d_in[26];
  const float* t_out_b   = (const float*)d_in[27];
  const float* fc_w      = (const float*)d_in[28];
  const float* fc_b      = (const float*)d_in[29];
  (void)n_in; (void)in_sizes; (void)out_size;

  float* wsp = (float*)d_ws;
  long off = 0;
  auto alloc = [&](long n){ float* p = wsp + off; off += n; return p; };
  auto alloc_us = [&](long n_us){ return (us*)alloc((n_us+1)/2); };

  float* emb = alloc(32768);
  unsigned* hpkA = (unsigned*)alloc(262144);   // packed h [512][512] u32
  unsigned* hpkB = (unsigned*)alloc(262144);
  float* dec_c = alloc(262144);
  unsigned* hbpkA = (unsigned*)alloc(131072);  // packed h [512][256] u32 (bwd dirs)
  unsigned* hbpkB = (unsigned*)alloc(131072);
  float* logits = alloc(3145728);
  // permuted scan weights [4H][KH+KX]
  us* wcF_hi = alloc_us(458752); us* wcF_lo = alloc_us(458752);   // char 1024x448
  us* wcB_hi = alloc_us(458752); us* wcB_lo = alloc_us(458752);
  us* wtF_hi = alloc_us(393216); us* wtF_lo = alloc_us(393216);   // tag 1024x384
  us* wtB_hi = alloc_us(393216); us* wtB_lo = alloc_us(393216);
  us* wd_hi  = alloc_us(1310720); us* wd_lo = alloc_us(1310720);  // dec 2048x640
  // attn weight splits
  us* cinw_hi  = alloc_us(786432); us* cinw_lo  = alloc_us(786432);
  us* coutw_hi = alloc_us(262144); us* coutw_lo = alloc_us(262144);
  us* tinw_hi  = alloc_us(786432); us* tinw_lo  = alloc_us(786432);
  us* toutw_hi = alloc_us(262144); us* toutw_lo = alloc_us(262144);
  us* fcw_hi   = alloc_us(131072); us* fcw_lo   = alloc_us(131072);
  us* labels_hi= alloc_us(3145728);us* labels_lo= alloc_us(3145728);  // time-major [48][512][128]
  us* chout_hi = alloc_us(12582912);
  us* tgout_hi = alloc_us(4194304);
  us* hs_hi    = alloc_us(12582912);
  unsigned* cnts = (unsigned*)alloc(1024);     // 3 x (8x32 local + global)
  float* arena = alloc(26345472);
  long needed_bytes = off * 4;
  if ((long)ws_size < needed_bytes) {
    hipLaunchKernelGGL(zero_k, dim3(64), dim3(256), 0, stream, (float*)d_out, (long)128);
    return;
  }

  // arena overlays (phases strictly sequential)
  us* cs_hi = (us*)arena;                      // time-major [48][512][192]
  us* cs_lo = (us*)(arena + 2359296);
  us* ts_hi = (us*)arena;                      // time-major [16][512][128]
  us* ts_lo = (us*)(arena + 524288);
  float* qh = arena;
  float* kh = arena + 12582912;
  float* vh = qh;
  us* opv_hi = (us*)(arena + 12582912);
  us* opv_lo = (us*)(arena + 18874368);
  us* ca_hi  = (us*)arena;
  us* ca_lo  = (us*)(arena + 6291456);
  float* sc_s = arena + 25165824;

  auto SPLIT = [&](const float* src, us* hi, us* lo, long n){
    hipLaunchKernelGGL(split_k, dim3(256), dim3(256), 0, stream, src, hi, lo, n);
  };
  auto PERM = [&](const float* Whh, const float* Wih, us* hi, us* lo, int H, int KH, int KX){
    hipLaunchKernelGGL(permsplit_k, dim3(1024), dim3(256), 0, stream, Whh, Wih, hi, lo, H, KH, KX);
  };
  auto MS = [&](int AS, const us* Ah, const us* Al, const us* Wh, const us* Wl,
                float* Cf, us* Chi, us* Clo, const float* bias,
                int M,int N,int K,int lda,int ldb,int ldc,int accf){
    dim3 gr(N/128, M/128);
    if (AS==1) hipLaunchKernelGGL((gemm_ms_k<1>), gr, dim3(256), 0, stream,
                                  Ah,Al,Wh,Wl,Cf,Chi,Clo,bias,M,N,K,lda,ldb,ldc,accf);
    else       hipLaunchKernelGGL((gemm_ms_k<2>), gr, dim3(256), 0, stream,
                                  Ah,Al,Wh,Wl,Cf,Chi,Clo,bias,M,N,K,lda,ldb,ldc,accf);
  };
  auto MSW = [&](int AS, const us* Ah, const us* Al, const us* Wh, const us* Wl,
                 float* Cf, us* Chi, us* Clo, const float* bias,
                 int M,int K,int lda,int ldb,int ldc){
    dim3 gr(M/128);
    if (AS==1) hipLaunchKernelGGL((gemm_msw_k<1>), gr, dim3(1024), 0, stream,
                                  Ah,Al,Wh,Wl,Cf,Chi,Clo,bias,K,lda,ldb,ldc);
    else       hipLaunchKernelGGL((gemm_msw_k<2>), gr, dim3(1024), 0, stream,
                                  Ah,Al,Wh,Wl,Cf,Chi,Clo,bias,K,lda,ldb,ldc);
  };

  // ---- prep: weight permute/splits ----
  PERM(c_whh_f, c_wih_f, wcF_hi, wcF_lo, 256, 256, 192);
  PERM(c_whh_b, c_wih_b, wcB_hi, wcB_lo, 256, 256, 192);
  PERM(t_whh_f, t_wih_f, wtF_hi, wtF_lo, 256, 256, 128);
  PERM(t_whh_b, t_wih_b, wtB_hi, wtB_lo, 256, 256, 128);
  PERM(cell_whh, cell_wih, wd_hi, wd_lo, 512, 512, 128);
  SPLIT(c_in_w,  cinw_hi,  cinw_lo,  786432);
  SPLIT(c_out_w, coutw_hi, coutw_lo, 262144);
  SPLIT(t_in_w,  tinw_hi,  tinw_lo,  786432);
  SPLIT(t_out_w, toutw_hi, toutw_lo, 262144);
  SPLIT(fc_w,    fcw_hi,   fcw_lo,   131072);
  hipLaunchKernelGGL(tsplit_k, dim3(1024), dim3(256), 0, stream, labels, labels_hi, labels_lo, 512, 48, 128);

  // ---- emb + zero init states/counters ----
  hipLaunchKernelGGL(emb_k, dim3(512), dim3(64), 0, stream, li, lang_emb, emb);
  hipLaunchKernelGGL(zero_k, dim3(256), dim3(256), 0, stream, (float*)hpkA, (long)262144);
  hipLaunchKernelGGL(zero_k, dim3(128), dim3(256), 0, stream, (float*)hbpkA, (long)131072);
  hipLaunchKernelGGL(zero_k, dim3(4), dim3(256), 0, stream, (float*)cnts, (long)1024);

  // ---- char phase: time-major concat, persistent fwd+bwd scan (256 WGs) ----
  {
    long tot = 512l*48*192;
    hipLaunchKernelGGL(build_concat_k, dim3((unsigned)((tot+255)/256)), dim3(256), 0, stream,
                       char_seq, emb, cs_hi, cs_lo, 512, 48, 128, 64, tot);
  }
  {
    ScanDir F, Bd;
    F.Whi=wcF_hi; F.Wlo=wcF_lo; F.bias=c_b_f;
    F.Xh=cs_hi; F.Xl=cs_lo; F.xrev=0; F.skip_x_t0=0;
    F.hpkA=hpkA; F.hpkB=hpkB; F.ldw=512;
    F.c0=nullptr; F.cfin=dec_c;
    F.out=chout_hi; F.ldo=512; F.otstride=262144; F.H=256;
    Bd.Whi=wcB_hi; Bd.Wlo=wcB_lo; Bd.bias=c_b_b;
    Bd.Xh=cs_hi; Bd.Xl=cs_lo; Bd.xrev=1; Bd.skip_x_t0=0;
    Bd.hpkA=hbpkA; Bd.hpkB=hbpkB; Bd.ldw=256;
    Bd.c0=nullptr; Bd.cfin=nullptr;
    Bd.out=chout_hi+256; Bd.ldo=512; Bd.otstride=262144; Bd.H=256;
    hipLaunchKernelGGL((scan_k<256,192>), dim3(256), dim3(256), 0, stream, F, Bd, 2, 48, cnts, cnts+256);
  }

  // ---- tag phase ----
  hipLaunchKernelGGL(zero_k, dim3(128), dim3(256), 0, stream, (float*)hbpkA, (long)131072);
  {
    long tot = 512l*16*128;
    hipLaunchKernelGGL(build_concat_k, dim3((unsigned)((tot+255)/256)), dim3(256), 0, stream,
                       tagset, emb, ts_hi, ts_lo, 512, 16, 64, 64, tot);
  }
  {
    ScanDir F, Bd;
    F.Whi=wtF_hi; F.Wlo=wtF_lo; F.bias=t_b_f;
    F.Xh=ts_hi; F.Xl=ts_lo; F.xrev=0; F.skip_x_t0=0;
    F.hpkA=hpkA+256; F.hpkB=hpkB+256; F.ldw=512;
    F.c0=nullptr; F.cfin=dec_c+256;
    F.out=tgout_hi; F.ldo=512; F.otstride=262144; F.H=256;
    Bd.Whi=wtB_hi; Bd.Wlo=wtB_lo; Bd.bias=t_b_b;
    Bd.Xh=ts_hi; Bd.Xl=ts_lo; Bd.xrev=1; Bd.skip_x_t0=0;
    Bd.hpkA=hbpkA; Bd.hpkB=hbpkB; Bd.ldw=256;
    Bd.c0=nullptr; Bd.cfin=nullptr;
    Bd.out=tgout_hi+256; Bd.ldo=512; Bd.otstride=262144; Bd.H=256;
    hipLaunchKernelGGL((scan_k<256,128>), dim3(256), dim3(256), 0, stream, F, Bd, 2, 16, cnts+288, cnts+544);
  }

  // ---- decoder (h0 in hpkA, c0 in dec_c) ----
  {
    ScanDir D;
    D.Whi=wd_hi; D.Wlo=wd_lo; D.bias=cell_b;
    D.Xh=labels_hi; D.Xl=labels_lo; D.xrev=0; D.skip_x_t0=1;
    D.hpkA=hpkA; D.hpkB=hpkB; D.ldw=512;
    D.c0=dec_c; D.cfin=nullptr;
    D.out=hs_hi; D.ldo=512; D.otstride=262144; D.H=512;
    hipLaunchKernelGGL((scan_k<512,128>), dim3(256), dim3(256), 0, stream, D, D, 1, 48, cnts+576, cnts+832);
  }

  const float scale = 0.044194173824159216f; // 1/sqrt(512)

  // ---- attentions + fc ----
  for (int which=0; which<2; ++which){
    const float* in_b  = which ? t_in_b  : c_in_b;
    const float* out_b = which ? t_out_b : c_out_b;
    const us* inw_hi = which ? tinw_hi : cinw_hi;
    const us* inw_lo = which ? tinw_lo : cinw_lo;
    const us* outw_hi= which ? toutw_hi: coutw_hi;
    const us* outw_lo= which ? toutw_lo: coutw_lo;
    const us* src    = which ? tgout_hi: chout_hi;
    int Mkv = which ? 8192 : 24576;
    int LK  = which ? 16 : 48;
    MSW(1, hs_hi, nullptr, inw_hi, inw_lo, qh, nullptr, nullptr, in_b,
        24576,512, 512,512,512);
    MSW(1, src, nullptr, inw_hi + (long)512*512, inw_lo + (long)512*512, kh, nullptr, nullptr, in_b+512,
        Mkv,512, 512,512,512);
    if (LK==48) hipLaunchKernelGGL((attn_scores_k<48>), dim3(512), dim3(256), 0, stream, qh, kh, sc_s, scale);
    else        hipLaunchKernelGGL((attn_scores_k<16>), dim3(512), dim3(256), 0, stream, qh, kh, sc_s, scale);
    hipLaunchKernelGGL(softmax_rows_k, dim3((24576+255)/256), dim3(256), 0, stream, sc_s, 24576, LK);
    MSW(1, src, nullptr, inw_hi + (long)1024*512, inw_lo + (long)1024*512, vh, nullptr, nullptr, in_b+1024,
        Mkv,512, 512,512,512);
    if (LK==48) hipLaunchKernelGGL((attn_av_k<48>), dim3(512,2), dim3(256), 0, stream, sc_s, vh, opv_hi, opv_lo);
    else        hipLaunchKernelGGL((attn_av_k<16>), dim3(512,2), dim3(256), 0, stream, sc_s, vh, opv_hi, opv_lo);
    MSW(2, opv_hi, opv_lo, outw_hi, outw_lo, nullptr, ca_hi, ca_lo, out_b,
        24576,512, 512,512,512);
    MS(2, ca_hi, ca_lo, fcw_hi + which*512, fcw_lo + which*512, logits, nullptr, nullptr,
       which ? nullptr : fc_b, 24576,128,512, 512,1024,128, which);
  }

  // ---- entmax 1.5 + transpose to [B, SC, 128] ----
  hipLaunchKernelGGL(entmax_k, dim3(6144), dim3(256), 0, stream, logits, (float*)d_out);
}